// Round 10
// baseline (1749.025 us; speedup 1.0000x reference)
//
#include <hip/hip_runtime.h>
#include <math.h>

#define T_STEPS 32768
#define N_NEUR  1024
#define FILT_LEN 200
#define NSEGM   128          // macro-segments of 256 scan steps
#define SEGM    256

typedef float f32x4 __attribute__((ext_vector_type(4)));

__device__ __forceinline__ float waveMax(float v) {
#pragma unroll
    for (int off = 32; off > 0; off >>= 1) v = fmaxf(v, __shfl_xor(v, off));
    return v;
}
__device__ __forceinline__ float waveSum(float v) {
#pragma unroll
    for (int off = 32; off > 0; off >>= 1) v += __shfl_xor(v, off);
    return v;
}
__device__ __forceinline__ int waveSumI(int v) {
#pragma unroll
    for (int off = 32; off > 0; off >>= 1) v += __shfl_xor(v, off);
    return v;
}

// ---------------- noise: 200-tap causal FIR of noise_rand*0.2 ----------------
// NUMERICS FROZEN.
__global__ __launch_bounds__(256) void noise_kernel(
    const float* __restrict__ noise_rand, float* __restrict__ noise_out)
{
    __shared__ float s_filt[FILT_LEN];
    __shared__ float s_nr[256 + FILT_LEN - 1];
    const int tid = threadIdx.x;
    const int t0  = blockIdx.x * 256;

    if (tid < FILT_LEN) s_filt[tid] = expf(-((float)tid * 0.05f));
    for (int i = tid; i < 256 + FILT_LEN - 1; i += 256) {
        int k = t0 - (FILT_LEN - 1) + i;
        s_nr[i] = (k >= 0) ? noise_rand[k] * 0.2f : 0.0f;
    }
    __syncthreads();

    const int t = t0 + tid;
    float acc = 0.0f;
#pragma unroll 4
    for (int j = FILT_LEN - 1; j >= 0; --j) {
        acc = fmaf(s_nr[tid + (FILT_LEN - 1) - j], s_filt[j], acc);
    }
    noise_out[t] = acc;
}

// ======== scan-wave code generation: NO arrays, all named registers =========
#define DECL_BANK(P) f32x4 P##0,P##1,P##2,P##3,P##4,P##5,P##6,P##7, \
                           P##8,P##9,P##10,P##11,P##12,P##13,P##14,P##15;

#define LOAD16(P, SB, OFF) do { \
    const f32x4* _sv = reinterpret_cast<const f32x4*>(&(SB)[OFF]); \
    P##0=_sv[0];  P##1=_sv[1];  P##2=_sv[2];  P##3=_sv[3];  \
    P##4=_sv[4];  P##5=_sv[5];  P##6=_sv[6];  P##7=_sv[7];  \
    P##8=_sv[8];  P##9=_sv[9];  P##10=_sv[10]; P##11=_sv[11]; \
    P##12=_sv[12]; P##13=_sv[13]; P##14=_sv[14]; P##15=_sv[15]; } while (0)

// one recurrence step, frozen numerics: mul-then-add, cmp->cndmask chain;
// predicated keep (lane==I literal) collects this step's inh into lane I
#define STEP1(TH, I) { bool _sp = inh < (TH); \
    float _a = __fmul_rn(inh, F); \
    float _b = __fadd_rn(_a, 3000.0f); \
    inh = _sp ? _b : _a; \
    keep = (lane == (I)) ? inh : keep; }

#define STEP4(V, I0) STEP1((V)[0], (I0)) STEP1((V)[1], (I0)+1) \
                     STEP1((V)[2], (I0)+2) STEP1((V)[3], (I0)+3)

#define CH64(P) \
    STEP4(P##0,  0) STEP4(P##1,  4) STEP4(P##2,  8) STEP4(P##3, 12) \
    STEP4(P##4, 16) STEP4(P##5, 20) STEP4(P##6, 24) STEP4(P##7, 28) \
    STEP4(P##8, 32) STEP4(P##9, 36) STEP4(P##10,40) STEP4(P##11,44) \
    STEP4(P##12,48) STEP4(P##13,52) STEP4(P##14,56) STEP4(P##15,60)

// spike <=> inh' >= 2500 (post-spike >= 3000; max no-spike <= ~3015*F = 2468)
#define EMIT(BROW) { int _r = (BROW) + lane; \
    inh_out[_r] = keep; \
    if (keep >= 2500.0f) out_spikes[(size_t)_r * N_NEUR + idxv] = 1.0f; }

// poll 256 rows of segment at NB (4 per lane) until all thr non-NaN, then
// acquire-fence and bounce them into LDS buffer SB
#define POLL_BOUNCE(NB, SB) { \
    float q0, q1, q2, q3; \
    for (;;) { \
        q0 = __hip_atomic_load(&thr_ws[(NB) + 4*lane + 0], __ATOMIC_RELAXED, __HIP_MEMORY_SCOPE_AGENT); \
        q1 = __hip_atomic_load(&thr_ws[(NB) + 4*lane + 1], __ATOMIC_RELAXED, __HIP_MEMORY_SCOPE_AGENT); \
        q2 = __hip_atomic_load(&thr_ws[(NB) + 4*lane + 2], __ATOMIC_RELAXED, __HIP_MEMORY_SCOPE_AGENT); \
        q3 = __hip_atomic_load(&thr_ws[(NB) + 4*lane + 3], __ATOMIC_RELAXED, __HIP_MEMORY_SCOPE_AGENT); \
        if (__all(((q0==q0) & (q1==q1)) & ((q2==q2) & (q3==q3)))) break; \
        __builtin_amdgcn_s_sleep(8); \
    } \
    __builtin_amdgcn_fence(__ATOMIC_ACQUIRE, "agent"); \
    f32x4 _qv; _qv[0]=q0; _qv[1]=q1; _qv[2]=q2; _qv[3]=q3; \
    reinterpret_cast<f32x4*>(&(SB)[4*lane])[0] = _qv; }

// ---------------- fused rows + sequential scan (producer-consumer) ----------
// thr_ws pre-memset to NaN (0xFF). Producers release-store real thr; the scan
// wave (block 0, wave 0) treats non-NaN as "row ready". Protocol proven r6/r7.
__global__ __launch_bounds__(256) void fused_kernel(
    const float* __restrict__ inputs, const float* __restrict__ noise,
    const float* __restrict__ u_mult, const float* __restrict__ rand_val,
    float* __restrict__ out_spikes, float* __restrict__ inh_out,
    float* __restrict__ thr_ws, int* __restrict__ idx_ws)
{
    __shared__ __align__(16) float sbuf[2][SEGM];   // per-lane -> uniform bounce

    if (blockIdx.x == 0) {
        // ================= scan wave =================
        if (threadIdx.x >= 64) return;
        const int lane = threadIdx.x;
        const float F = 0.8187307530779818f;        // (float)exp(-DT/INH_TAU)
        __builtin_amdgcn_s_setprio(1);

        DECL_BANK(A) DECL_BANK(B)
        float inh = 0.0f, keep = 0.0f;
        int idxv = 0;

        // prologue: stage segment 0, preload bank0 -> A
        POLL_BOUNCE(0, sbuf[0]);
        LOAD16(A, sbuf[0], 0);

        for (int k = 0; k < NSEGM; ++k) {
            float* sbc = sbuf[k & 1];
            float* sbn = sbuf[(k + 1) & 1];
            const int sb0 = k << 8;

            if (k + 1 < NSEGM) POLL_BOUNCE((k + 1) << 8, sbn);

            idxv = idx_ws[sb0 + lane];
            LOAD16(B, sbc, 64);                  // fill bank1 under chain bank0
            CH64(A); EMIT(sb0);

            idxv = idx_ws[sb0 + 64 + lane];
            LOAD16(A, sbc, 128);                 // bank2 under bank1
            CH64(B); EMIT(sb0 + 64);

            idxv = idx_ws[sb0 + 128 + lane];
            LOAD16(B, sbc, 192);                 // bank3 under bank2
            CH64(A); EMIT(sb0 + 128);

            idxv = idx_ws[sb0 + 192 + lane];
            LOAD16(A, sbn, 0);                   // next seg bank0 under bank3
            CH64(B); EMIT(sb0 + 192);
        }
        return;
    }

    // ================= rows wave (one wave per row; NUMERICS FROZEN) =========
    const int wid  = threadIdx.x >> 6;
    const int lane = threadIdx.x & 63;
    const int t    = (blockIdx.x - 1) * 4 + wid;

    const f32x4* row = reinterpret_cast<const f32x4*>(inputs + (size_t)t * N_NEUR);
    f32x4 x0 = __builtin_nontemporal_load(&row[lane]);
    f32x4 x1 = __builtin_nontemporal_load(&row[lane + 64]);
    f32x4 x2 = __builtin_nontemporal_load(&row[lane + 128]);
    f32x4 x3 = __builtin_nontemporal_load(&row[lane + 192]);

    // zero-fill this output row BEFORE the release (scatter ordered after it)
    f32x4 z = (f32x4){0.f, 0.f, 0.f, 0.f};
    f32x4* orow = reinterpret_cast<f32x4*>(out_spikes + (size_t)t * N_NEUR);
    __builtin_nontemporal_store(z, &orow[lane]);
    __builtin_nontemporal_store(z, &orow[lane + 64]);
    __builtin_nontemporal_store(z, &orow[lane + 128]);
    __builtin_nontemporal_store(z, &orow[lane + 192]);

    // ---- row max ----
    float m = fmaxf(
        fmaxf(fmaxf(fmaxf(x0[0], x0[1]), fmaxf(x0[2], x0[3])),
              fmaxf(fmaxf(x1[0], x1[1]), fmaxf(x1[2], x1[3]))),
        fmaxf(fmaxf(fmaxf(x2[0], x2[1]), fmaxf(x2[2], x2[3])),
              fmaxf(fmaxf(x3[0], x3[1]), fmaxf(x3[2], x3[3]))));
    m = waveMax(m);

    // ---- softmax numerators (no noise) + denominator ----
    float e00 = expf(x0[0] - m), e01 = expf(x0[1] - m), e02 = expf(x0[2] - m), e03 = expf(x0[3] - m);
    float e10 = expf(x1[0] - m), e11 = expf(x1[1] - m), e12 = expf(x1[2] - m), e13 = expf(x1[3] - m);
    float e20 = expf(x2[0] - m), e21 = expf(x2[1] - m), e22 = expf(x2[2] - m), e23 = expf(x2[3] - m);
    float e30 = expf(x3[0] - m), e31 = expf(x3[1] - m), e32 = expf(x3[2] - m), e33 = expf(x3[3] - m);
    float s0 = ((e00 + e01) + e02) + e03;
    float s1 = ((e10 + e11) + e12) + e13;
    float s2 = ((e20 + e21) + e22) + e23;
    float s3 = ((e30 + e31) + e32) + e33;
    const float sum_e = waveSum(((s0 + s1) + s2) + s3);

    // ---- logsumexp over y = x + noise; max(y) = fl(m + nz) by monotonicity ----
    const float nz = noise[t];
    const float my = m + nz;
    float f0 = ((expf((x0[0] + nz) - my) + expf((x0[1] + nz) - my))
              +  expf((x0[2] + nz) - my)) + expf((x0[3] + nz) - my);
    float f1 = ((expf((x1[0] + nz) - my) + expf((x1[1] + nz) - my))
              +  expf((x1[2] + nz) - my)) + expf((x1[3] + nz) - my);
    float f2 = ((expf((x2[0] + nz) - my) + expf((x2[1] + nz) - my))
              +  expf((x2[2] + nz) - my)) + expf((x2[3] + nz) - my);
    float f3 = ((expf((x3[0] + nz) - my) + expf((x3[1] + nz) - my))
              +  expf((x3[2] + nz) - my)) + expf((x3[3] + nz) - my);
    const float sum_ey = waveSum(((f0 + f1) + f2) + f3);

    // ---- p = e / sum_e (true division, per reference), hierarchical prefix ----
    float p00 = e00 / sum_e, p01 = e01 / sum_e, p02 = e02 / sum_e, p03 = e03 / sum_e;
    float p10 = e10 / sum_e, p11 = e11 / sum_e, p12 = e12 / sum_e, p13 = e13 / sum_e;
    float p20 = e20 / sum_e, p21 = e21 / sum_e, p22 = e22 / sum_e, p23 = e23 / sum_e;
    float p30 = e30 / sum_e, p31 = e31 / sum_e, p32 = e32 / sum_e, p33 = e33 / sum_e;

    float c00 = p00, c01 = c00 + p01, c02 = c01 + p02, c03 = c02 + p03;
    float c10 = p10, c11 = c10 + p11, c12 = c11 + p12, c13 = c12 + p13;
    float c20 = p20, c21 = c20 + p21, c22 = c21 + p22, c23 = c22 + p23;
    float c30 = p30, c31 = c30 + p31, c32 = c31 + p32, c33 = c32 + p33;

    float g0 = c03, g1 = c13, g2 = c23, g3 = c33;
    float i0 = g0, i1 = g1, i2 = g2, i3 = g3;
#pragma unroll
    for (int off = 1; off < 64; off <<= 1) {
        float v0 = __shfl_up(i0, off), v1 = __shfl_up(i1, off);
        float v2 = __shfl_up(i2, off), v3 = __shfl_up(i3, off);
        if (lane >= off) { i0 += v0; i1 += v1; i2 += v2; i3 += v3; }
    }
    float tot0 = __shfl(i0, 63), tot1 = __shfl(i1, 63), tot2 = __shfl(i2, 63);
    float ex0 = __shfl_up(i0, 1), ex1 = __shfl_up(i1, 1),
          ex2 = __shfl_up(i2, 1), ex3 = __shfl_up(i3, 1);
    if (lane == 0) { ex0 = 0.f; ex1 = 0.f; ex2 = 0.f; ex3 = 0.f; }
    float J1 = tot0, J2 = J1 + tot1, J3 = J2 + tot2;
    float b0 = ex0;
    float b1 = J1 + ex1;
    float b2 = J2 + ex2;
    float b3 = J3 + ex3;

    const float u = u_mult[t];
    int cnt = (int)(b0 + c00 < u) + (int)(b0 + c01 < u) + (int)(b0 + c02 < u) + (int)(b0 + c03 < u)
            + (int)(b1 + c10 < u) + (int)(b1 + c11 < u) + (int)(b1 + c12 < u) + (int)(b1 + c13 < u)
            + (int)(b2 + c20 < u) + (int)(b2 + c21 < u) + (int)(b2 + c22 < u) + (int)(b2 + c23 < u)
            + (int)(b3 + c30 < u) + (int)(b3 + c31 < u) + (int)(b3 + c32 < u) + (int)(b3 + c33 < u);
    cnt = waveSumI(cnt);

    if (lane == 0) {
        int idx = (cnt >= N_NEUR) ? 0 : cnt;   // all-False -> argmax returns 0
        idx_ws[t] = idx;
        float log_total = my + logf(sum_ey);
        float thrv = (log_total + (float)(-6.907755278982137)) - logf(rand_val[t]);
        // release publish: orders zero-fill + idx store before thr becomes non-NaN
        __hip_atomic_store(&thr_ws[t], thrv, __ATOMIC_RELEASE, __HIP_MEMORY_SCOPE_AGENT);
    }
}

extern "C" void kernel_launch(void* const* d_in, const int* in_sizes, int n_in,
                              void* d_out, int out_size, void* d_ws, size_t ws_size,
                              hipStream_t stream)
{
    const float* inputs     = (const float*)d_in[0];
    const float* noise_rand = (const float*)d_in[1];
    const float* u_mult     = (const float*)d_in[2];
    const float* rand_val   = (const float*)d_in[3];

    float* out_spk   = (float*)d_out;
    float* out_inh   = out_spk + (size_t)T_STEPS * N_NEUR;
    float* out_noise = out_inh + T_STEPS;

    float* thr_ws = (float*)d_ws;
    int*   idx_ws = (int*)((char*)d_ws + (size_t)T_STEPS * 4);

    // thr sentinel = NaN (0xFF bytes); rows overwrite with real (finite) thr
    hipMemsetAsync(thr_ws, 0xFF, (size_t)T_STEPS * 4, stream);
    noise_kernel<<<T_STEPS / 256, 256, 0, stream>>>(noise_rand, out_noise);
    fused_kernel<<<T_STEPS / 4 + 1, 256, 0, stream>>>(
        inputs, out_noise, u_mult, rand_val,
        out_spk, out_inh, thr_ws, idx_ws);
}